// Round 3
// baseline (59543.817 us; speedup 1.0000x reference)
//
#include <hip/hip_runtime.h>

// Problem constants
#define T_SEQ   8192
#define N_RES   2048
#define K_IN    512

// Geometry: 256 blocks (1 per CU) x 256 threads (4 waves); 2 rows per wave.
#define G_BLOCKS 256
#define B_THREADS 256
static_assert(G_BLOCKS * 8 == N_RES, "row partition mismatch");

#define INV_SQRT_N 0.022097086912079612f

// Phase encoding: packet float e = phi*(v + ENC_OFF), phi = +/-1 alternating
// per ring-slot generation. |v| <= 0.0222 -> |e| in [0.078, 0.122].
// Ready test: phi_expected * e > ENC_THR. Stale packet (previous generation in
// this slot) has opposite phi -> phi_expected*e <= -0.078. Zero-init -> 0.
#define ENC_OFF 0.1f
#define ENC_THR 0.05f

typedef unsigned long long u64;
typedef unsigned int u32;

__device__ __forceinline__ float fast_tanh(float v) {
    float e = __expf(2.0f * v);
    return 1.0f - 2.0f / (e + 1.0f);
}

// ring: [2][N_RES/2] u64; entry c of slot s holds encoded state elements
// (2c, 2c+1) of the generation currently mapped to slot s (= t & 1).
__global__ __launch_bounds__(B_THREADS, 1)
void reservoir_flow3(const float* __restrict__ input,   // [T_SEQ][K_IN]
                     const float* __restrict__ state0,  // [N_RES]
                     const float* __restrict__ W_in,    // [N_RES][K_IN]
                     const float* __restrict__ W_res,   // [N_RES][N_RES]
                     float* __restrict__ out,           // [T_SEQ+1][N_RES]
                     u64* __restrict__ ring)
{
    const int tid  = threadIdx.x;
    const int lane = tid & 63;
    const int wave = tid >> 6;
    const int blk  = blockIdx.x;
    const int r0   = blk * 8 + wave * 2;      // this wave's two rows (even base)

    // ---- persistent weights: lane owns contiguous columns [32*lane, 32*lane+31]
    // for W_res rows r0/r0+1, and [8*lane, 8*lane+7] for W_in rows r0/r0+1.
    float4 w0[8], w1[8], wi0[2], wi1[2];
    {
        const float* p0 = W_res + (size_t)r0 * N_RES + 32 * lane;
        const float* p1 = p0 + N_RES;
        #pragma unroll
        for (int i = 0; i < 8; ++i) {
            w0[i] = *reinterpret_cast<const float4*>(p0 + 4 * i);
            w1[i] = *reinterpret_cast<const float4*>(p1 + 4 * i);
        }
        const float* q0 = W_in + (size_t)r0 * K_IN + 8 * lane;
        const float* q1 = q0 + K_IN;
        #pragma unroll
        for (int i = 0; i < 2; ++i) {
            wi0[i] = *reinterpret_cast<const float4*>(q0 + 4 * i);
            wi1[i] = *reinterpret_cast<const float4*>(q1 + 4 * i);
        }
    }

    // out row 0 = initial state
    if (blk == 0)
        for (int j = tid; j < N_RES; j += B_THREADS) out[j] = state0[j];

    // x row 0
    float4 xa = *reinterpret_cast<const float4*>(input + 8 * lane);
    float4 xb = *reinterpret_cast<const float4*>(input + 8 * lane + 4);

    for (int t = 0; t < T_SEQ; ++t) {
        // ---- input contribution (x was prefetched last iteration) ----
        float acc0 = 0.0f, acc1 = 0.0f;
        acc0 = fmaf(wi0[0].x, xa.x, acc0); acc0 = fmaf(wi0[0].y, xa.y, acc0);
        acc0 = fmaf(wi0[0].z, xa.z, acc0); acc0 = fmaf(wi0[0].w, xa.w, acc0);
        acc0 = fmaf(wi0[1].x, xb.x, acc0); acc0 = fmaf(wi0[1].y, xb.y, acc0);
        acc0 = fmaf(wi0[1].z, xb.z, acc0); acc0 = fmaf(wi0[1].w, xb.w, acc0);
        acc1 = fmaf(wi1[0].x, xa.x, acc1); acc1 = fmaf(wi1[0].y, xa.y, acc1);
        acc1 = fmaf(wi1[0].z, xa.z, acc1); acc1 = fmaf(wi1[0].w, xa.w, acc1);
        acc1 = fmaf(wi1[1].x, xb.x, acc1); acc1 = fmaf(wi1[1].y, xb.y, acc1);
        acc1 = fmaf(wi1[1].z, xb.z, acc1); acc1 = fmaf(wi1[1].w, xb.w, acc1);

        // ---- state contribution ----
        if (t == 0) {
            const float* sp = state0 + 32 * lane;
            #pragma unroll
            for (int i = 0; i < 8; ++i) {
                float4 s = *reinterpret_cast<const float4*>(sp + 4 * i);
                acc0 = fmaf(w0[i].x, s.x, acc0); acc0 = fmaf(w0[i].y, s.y, acc0);
                acc0 = fmaf(w0[i].z, s.z, acc0); acc0 = fmaf(w0[i].w, s.w, acc0);
                acc1 = fmaf(w1[i].x, s.x, acc1); acc1 = fmaf(w1[i].y, s.y, acc1);
                acc1 = fmaf(w1[i].z, s.z, acc1); acc1 = fmaf(w1[i].w, s.w, acc1);
            }
        } else {
            // fused poll+FMA: consume each packet the moment it arrives
            const u64* rp = ring + ((t & 1) << 10) + lane * 16;
            const float phi = ((t >> 1) & 1) ? -1.0f : 1.0f;
            u32 pend = 0xFFFFu;
            while (pend) {
                #pragma unroll
                for (int p = 0; p < 16; ++p) {
                    if (pend & (1u << p)) {
                        u64 e = __hip_atomic_load(rp + p, __ATOMIC_RELAXED,
                                                  __HIP_MEMORY_SCOPE_AGENT);
                        float lo = __uint_as_float((u32)e);
                        float hi = __uint_as_float((u32)(e >> 32));
                        if (phi * lo > ENC_THR && phi * hi > ENC_THR) {
                            float vlo = fmaf(phi, lo, -ENC_OFF);
                            float vhi = fmaf(phi, hi, -ENC_OFF);
                            // columns 2p, 2p+1 of this lane's 32-col chunk
                            float c0lo = (p & 1) ? w0[p >> 1].z : w0[p >> 1].x;
                            float c0hi = (p & 1) ? w0[p >> 1].w : w0[p >> 1].y;
                            float c1lo = (p & 1) ? w1[p >> 1].z : w1[p >> 1].x;
                            float c1hi = (p & 1) ? w1[p >> 1].w : w1[p >> 1].y;
                            acc0 = fmaf(c0lo, vlo, acc0);
                            acc0 = fmaf(c0hi, vhi, acc0);
                            acc1 = fmaf(c1lo, vlo, acc1);
                            acc1 = fmaf(c1hi, vhi, acc1);
                            pend &= ~(1u << p);
                        }
                    }
                }
            }
        }

        // prefetch next input row (latency hides under the reduce)
        if (t + 1 < T_SEQ) {
            const float* xr = input + (size_t)(t + 1) * K_IN + 8 * lane;
            xa = *reinterpret_cast<const float4*>(xr);
            xb = *reinterpret_cast<const float4*>(xr + 4);
        }

        // ---- full-wave butterfly reduce (both rows in flight) ----
        #pragma unroll
        for (int off = 32; off > 0; off >>= 1) {
            acc0 += __shfl_xor(acc0, off, 64);
            acc1 += __shfl_xor(acc1, off, 64);
        }

        // ---- finalize + publish (lane 0 emits both rows as one packet) ----
        float v0 = fast_tanh(acc0) * INV_SQRT_N;
        float v1 = fast_tanh(acc1) * INV_SQRT_N;
        if (lane == 0) {
            *reinterpret_cast<float2*>(out + (size_t)(t + 1) * N_RES + r0) =
                make_float2(v0, v1);
            float phin = (((t + 1) >> 1) & 1) ? -1.0f : 1.0f;
            u64 pk = (u64)__float_as_uint(phin * (v0 + ENC_OFF)) |
                     ((u64)__float_as_uint(phin * (v1 + ENC_OFF)) << 32);
            __hip_atomic_store(ring + (((t + 1) & 1) << 10) + (r0 >> 1), pk,
                               __ATOMIC_RELAXED, __HIP_MEMORY_SCOPE_AGENT);
        }
    }
}

extern "C" void kernel_launch(void* const* d_in, const int* in_sizes, int n_in,
                              void* d_out, int out_size, void* d_ws, size_t ws_size,
                              hipStream_t stream) {
    const float* input  = (const float*)d_in[0];
    const float* state0 = (const float*)d_in[1];
    const float* W_in   = (const float*)d_in[2];
    const float* W_res  = (const float*)d_in[3];
    float* out = (float*)d_out;
    u64* ring  = (u64*)d_ws;

    // zero = "not ready" for every phase; re-cleared on every call/replay
    hipMemsetAsync(d_ws, 0, 2 * (N_RES / 2) * sizeof(u64), stream);

    void* args[] = { (void*)&input, (void*)&state0, (void*)&W_in, (void*)&W_res,
                     (void*)&out, (void*)&ring };
    hipLaunchCooperativeKernel((const void*)reservoir_flow3,
                               dim3(G_BLOCKS), dim3(B_THREADS),
                               args, 0, stream);
}

// Round 4
// 25618.829 us; speedup vs baseline: 2.3242x; 2.3242x over previous
//
#include <hip/hip_runtime.h>

// Problem constants
#define T_SEQ   8192
#define N_RES   2048
#define K_IN    512

// Geometry: 128 blocks x 256 threads (4 waves); 16 rows/block, 4 rows/wave.
#define G_BLOCKS 128
#define B_THREADS 256
#define ROWS_PER_WAVE 4
#define ROWS_PER_BLOCK 16
static_assert(G_BLOCKS * ROWS_PER_BLOCK == N_RES, "row partition mismatch");

#define INV_SQRT_N 0.022097086912079612f

// Phase encoding: packet float e = phi*(v + ENC_OFF), phi alternates per ring
// generation (phi(g) = ((g>>1)&1) ? -1 : +1, slot = g&1). |v| <= 0.0222 so
// |e| in [0.078, 0.122]. Ready iff phi_expected*e > ENC_THR; stale (gen-2)
// packet has opposite phi -> reads as not-ready; zero-init -> not-ready.
#define ENC_OFF 0.1f
#define ENC_THR 0.05f

typedef unsigned long long u64;
typedef unsigned int u32;

__device__ __forceinline__ float fast_tanh(float v) {
    float e = __expf(2.0f * v);
    return 1.0f - 2.0f / (e + 1.0f);
}

// In-loop register pin: the "+v" OUTPUT is the only def reaching next
// iteration's uses, so the compiler cannot re-load the value from memory.
#define KEEP4(v) asm("" : "+v"((v).x), "+v"((v).y), "+v"((v).z), "+v"((v).w))

__global__ __launch_bounds__(B_THREADS, 1)
void reservoir_v4(const float* __restrict__ input,   // [T_SEQ][K_IN]
                  const float* __restrict__ state0,  // [N_RES]
                  const float* __restrict__ W_in,    // [N_RES][K_IN]
                  const float* __restrict__ W_res,   // [N_RES][N_RES]
                  float* __restrict__ out,           // [T_SEQ+1][N_RES]
                  u64* __restrict__ ring)            // [2][N_RES/2]
{
    const int tid  = threadIdx.x;
    const int lane = tid & 63;
    const int wave = tid >> 6;
    const int blk  = blockIdx.x;
    const int r0   = blk * ROWS_PER_BLOCK + wave * ROWS_PER_WAVE;

    __shared__ float s_lds[2][N_RES];   // double-buffered state (16 KB)

    // ---- persistent weights: lane l owns cols {4l+256i} ----
    float4 wr[ROWS_PER_WAVE][8];
    float4 wi[ROWS_PER_WAVE][2];
    #pragma unroll
    for (int k = 0; k < ROWS_PER_WAVE; ++k) {
        const float* rrow = W_res + (size_t)(r0 + k) * N_RES;
        #pragma unroll
        for (int i = 0; i < 8; ++i)
            wr[k][i] = *reinterpret_cast<const float4*>(rrow + 4 * lane + 256 * i);
        const float* irow = W_in + (size_t)(r0 + k) * K_IN;
        #pragma unroll
        for (int i = 0; i < 2; ++i)
            wi[k][i] = *reinterpret_cast<const float4*>(irow + 4 * lane + 256 * i);
    }

    // out row 0 = initial state
    if (blk == 0)
        for (int j = tid; j < N_RES; j += B_THREADS) out[j] = state0[j];

    // s_0 -> LDS buffer 0 (covered by the in-loop __syncthreads at t=0)
    #pragma unroll
    for (int i = 0; i < 8; ++i)
        s_lds[0][i * 256 + tid] = state0[i * 256 + tid];

    // x row 0 (layout matches wi columns {4l+256i})
    float4 xa = *reinterpret_cast<const float4*>(input + 4 * lane);
    float4 xb = *reinterpret_cast<const float4*>(input + 4 * lane + 256);

    for (int t = 0; t < T_SEQ; ++t) {
        const int buf = t & 1;

        // issue x_{t+1} prefetch before the spin so HBM latency hides under it
        float4 xna = xa, xnb = xb;
        if (t + 1 < T_SEQ) {
            const float* xr = input + (size_t)(t + 1) * K_IN;
            xna = *reinterpret_cast<const float4*>(xr + 4 * lane);
            xnb = *reinterpret_cast<const float4*>(xr + 4 * lane + 256);
        }

        if (t > 0) {
            // ---- paced coalesced poll: 4 u64/thread covers the 1024-entry slot ----
            const u64* rp = ring + (buf << 10);
            const float phi = ((t >> 1) & 1) ? -1.0f : 1.0f;
            float2 sv2[4];
            u32 pend = 0xFu;
            while (pend) {
                #pragma unroll
                for (int i = 0; i < 4; ++i) {
                    if (pend & (1u << i)) {
                        u64 e = __hip_atomic_load(rp + i * 256 + tid,
                                                  __ATOMIC_RELAXED, __HIP_MEMORY_SCOPE_AGENT);
                        float lo = __uint_as_float((u32)e);
                        float hi = __uint_as_float((u32)(e >> 32));
                        if (phi * lo > ENC_THR && phi * hi > ENC_THR) {
                            sv2[i] = make_float2(fmaf(phi, lo, -ENC_OFF),
                                                 fmaf(phi, hi, -ENC_OFF));
                            pend &= ~(1u << i);
                        }
                    }
                }
                if (pend) __builtin_amdgcn_s_sleep(1);   // ~64cy backoff: cut L3 hammering
            }
            #pragma unroll
            for (int i = 0; i < 4; ++i)
                *reinterpret_cast<float2*>(&s_lds[buf][2 * (i * 256 + tid)]) = sv2[i];
        }
        __syncthreads();

        // ---- input contribution ----
        float acc[ROWS_PER_WAVE];
        #pragma unroll
        for (int k = 0; k < ROWS_PER_WAVE; ++k) {
            float a = 0.0f;
            a = fmaf(wi[k][0].x, xa.x, a); a = fmaf(wi[k][0].y, xa.y, a);
            a = fmaf(wi[k][0].z, xa.z, a); a = fmaf(wi[k][0].w, xa.w, a);
            a = fmaf(wi[k][1].x, xb.x, a); a = fmaf(wi[k][1].y, xb.y, a);
            a = fmaf(wi[k][1].z, xb.z, a); a = fmaf(wi[k][1].w, xb.w, a);
            acc[k] = a;
        }

        // ---- state contribution from LDS (layout proven conflict-free in R2) ----
        float4 sv[8];
        #pragma unroll
        for (int i = 0; i < 8; ++i)
            sv[i] = *reinterpret_cast<const float4*>(&s_lds[buf][4 * lane + 256 * i]);
        #pragma unroll
        for (int k = 0; k < ROWS_PER_WAVE; ++k) {
            float a = acc[k];
            #pragma unroll
            for (int i = 0; i < 8; ++i) {
                a = fmaf(wr[k][i].x, sv[i].x, a);
                a = fmaf(wr[k][i].y, sv[i].y, a);
                a = fmaf(wr[k][i].z, sv[i].z, a);
                a = fmaf(wr[k][i].w, sv[i].w, a);
            }
            acc[k] = a;
        }

        // ---- full-wave butterfly reduce (4 rows in flight) ----
        #pragma unroll
        for (int off = 32; off > 0; off >>= 1) {
            #pragma unroll
            for (int k = 0; k < ROWS_PER_WAVE; ++k)
                acc[k] += __shfl_xor(acc[k], off, 64);
        }

        // ---- finalize: publish first (critical path), out store off-path ----
        const float v0 = fast_tanh(acc[0]) * INV_SQRT_N;
        const float v1 = fast_tanh(acc[1]) * INV_SQRT_N;
        const float v2 = fast_tanh(acc[2]) * INV_SQRT_N;
        const float v3 = fast_tanh(acc[3]) * INV_SQRT_N;
        const int   slotn = (t + 1) & 1;
        const float phin  = (((t + 1) >> 1) & 1) ? -1.0f : 1.0f;
        if (lane == 0) {
            u64 pk = (u64)__float_as_uint(phin * (v0 + ENC_OFF)) |
                     ((u64)__float_as_uint(phin * (v1 + ENC_OFF)) << 32);
            __hip_atomic_store(ring + (slotn << 10) + (r0 >> 1), pk,
                               __ATOMIC_RELAXED, __HIP_MEMORY_SCOPE_AGENT);
        } else if (lane == 1) {
            u64 pk = (u64)__float_as_uint(phin * (v2 + ENC_OFF)) |
                     ((u64)__float_as_uint(phin * (v3 + ENC_OFF)) << 32);
            __hip_atomic_store(ring + (slotn << 10) + (r0 >> 1) + 1, pk,
                               __ATOMIC_RELAXED, __HIP_MEMORY_SCOPE_AGENT);
        } else if (lane == 2) {
            *reinterpret_cast<float4*>(out + (size_t)(t + 1) * N_RES + r0) =
                make_float4(v0, v1, v2, v3);
        }

        // ---- pin weights across the back edge (defeats reload/remat) ----
        #pragma unroll
        for (int k = 0; k < ROWS_PER_WAVE; ++k) {
            #pragma unroll
            for (int i = 0; i < 8; ++i) KEEP4(wr[k][i]);
            KEEP4(wi[k][0]); KEEP4(wi[k][1]);
        }

        xa = xna; xb = xnb;
    }
}

extern "C" void kernel_launch(void* const* d_in, const int* in_sizes, int n_in,
                              void* d_out, int out_size, void* d_ws, size_t ws_size,
                              hipStream_t stream) {
    const float* input  = (const float*)d_in[0];
    const float* state0 = (const float*)d_in[1];
    const float* W_in   = (const float*)d_in[2];
    const float* W_res  = (const float*)d_in[3];
    float* out = (float*)d_out;
    u64* ring  = (u64*)d_ws;

    // zero = "not ready" for both phases; re-cleared on every call/replay
    hipMemsetAsync(d_ws, 0, 2 * (N_RES / 2) * sizeof(u64), stream);

    void* args[] = { (void*)&input, (void*)&state0, (void*)&W_in, (void*)&W_res,
                     (void*)&out, (void*)&ring };
    hipLaunchCooperativeKernel((const void*)reservoir_v4,
                               dim3(G_BLOCKS), dim3(B_THREADS),
                               args, 0, stream);
}